// Round 11
// baseline (83.731 us; speedup 1.0000x reference)
//
#include <hip/hip_runtime.h>
#include <stdint.h>

#define DIM 256
#define NQ 8
#define NLAYERS 3
#define NPAIRS 4

typedef float f32x4 __attribute__((ext_vector_type(4)));
typedef long lng2 __attribute__((ext_vector_type(2)));  // 16 B = two i64 fp8 frags

// ---------------------------------------------------------------------------
// Kernel 1: build U (256x256 complex fp32), barrier-free, one WAVE per basis
// column, one column per 64-thread block. Lane holds 4 amplitudes
// a = r*64 + lane. Wire w <-> bit (7-w) of a: wire0 -> r bit1, wire1 -> r
// bit0 (in-register), wire2..7 -> lane bits 5..0 (shfl_xor).
// Algebra verified rounds 6-10 (passed).
// ---------------------------------------------------------------------------
__global__ __launch_bounds__(64) void build_U(const float* __restrict__ params,
                                              float* __restrict__ Ure,
                                              float* __restrict__ Uim) {
  const int lane = threadIdx.x;
  const int col = blockIdx.x;

  float ar[4], ai[4];
#pragma unroll
  for (int r = 0; r < 4; ++r) {
    ar[r] = (r * 64 + lane == col) ? 1.0f : 0.0f;
    ai[r] = 0.0f;
  }

  for (int layer = 0; layer < NLAYERS; ++layer) {
#pragma unroll
    for (int p = 0; p < NPAIRS; ++p) {
      const int base = (layer * NPAIRS + p) * 4;
      const float p0 = params[base + 0], p1 = params[base + 1];
      const float p2 = params[base + 2], p3 = params[base + 3];
      const int czm = (p == 1) ? 32 : (p == 2) ? 8 : 2;   // ctrl / RZ_i bit
      const int txr = (p == 1) ? 16 : (p == 2) ? 4 : 1;   // target xor / bit

      { // RZ(p0) on wire i = 2p
        float s0, c0;
        __sincosf(0.5f * p0, &s0, &c0);
        if (p == 0) {
#pragma unroll
          for (int r = 0; r < 4; ++r) {
            const float sg = (r >= 2) ? s0 : -s0;  // r bit1
            const float nr = ar[r] * c0 - ai[r] * sg;
            ai[r] = ar[r] * sg + ai[r] * c0;
            ar[r] = nr;
          }
        } else {
          const float sg = (lane & czm) ? s0 : -s0;
#pragma unroll
          for (int r = 0; r < 4; ++r) {
            const float nr = ar[r] * c0 - ai[r] * sg;
            ai[r] = ar[r] * sg + ai[r] * c0;
            ar[r] = nr;
          }
        }
      }
      { // RX(p1) on wire j = 2p+1
        float s0, c0;
        __sincosf(0.5f * p1, &s0, &c0);
        if (p == 0) {  // partner r^1
          float nr[4], ni[4];
#pragma unroll
          for (int r = 0; r < 4; ++r) {
            nr[r] = c0 * ar[r] + s0 * ai[r ^ 1];
            ni[r] = c0 * ai[r] - s0 * ar[r ^ 1];
          }
#pragma unroll
          for (int r = 0; r < 4; ++r) { ar[r] = nr[r]; ai[r] = ni[r]; }
        } else {  // partner lane^txr
#pragma unroll
          for (int r = 0; r < 4; ++r) {
            const float pr = __shfl_xor(ar[r], txr);
            const float pi = __shfl_xor(ai[r], txr);
            ar[r] = c0 * ar[r] + s0 * pi;
            ai[r] = c0 * ai[r] - s0 * pr;
          }
        }
      }
      { // CNOT(i -> j)
        if (p == 0) {  // ctrl r bit1: swap amp[2] <-> amp[3]
          const float tr = ar[2], ti = ai[2];
          ar[2] = ar[3]; ai[2] = ai[3];
          ar[3] = tr;    ai[3] = ti;
        } else {
#pragma unroll
          for (int r = 0; r < 4; ++r) {
            const float vr = __shfl_xor(ar[r], txr);
            const float vi = __shfl_xor(ai[r], txr);
            ar[r] = (lane & czm) ? vr : ar[r];
            ai[r] = (lane & czm) ? vi : ai[r];
          }
        }
      }
      { // RZ(p2) on wire j
        float s0, c0;
        __sincosf(0.5f * p2, &s0, &c0);
        if (p == 0) {
#pragma unroll
          for (int r = 0; r < 4; ++r) {
            const float sg = (r & 1) ? s0 : -s0;  // r bit0
            const float nr = ar[r] * c0 - ai[r] * sg;
            ai[r] = ar[r] * sg + ai[r] * c0;
            ar[r] = nr;
          }
        } else {
          const float sg = (lane & txr) ? s0 : -s0;
#pragma unroll
          for (int r = 0; r < 4; ++r) {
            const float nr = ar[r] * c0 - ai[r] * sg;
            ai[r] = ar[r] * sg + ai[r] * c0;
            ar[r] = nr;
          }
        }
      }
      { // RX(p3) on wire j
        float s0, c0;
        __sincosf(0.5f * p3, &s0, &c0);
        if (p == 0) {
          float nr[4], ni[4];
#pragma unroll
          for (int r = 0; r < 4; ++r) {
            nr[r] = c0 * ar[r] + s0 * ai[r ^ 1];
            ni[r] = c0 * ai[r] - s0 * ar[r ^ 1];
          }
#pragma unroll
          for (int r = 0; r < 4; ++r) { ar[r] = nr[r]; ai[r] = ni[r]; }
        } else {
#pragma unroll
          for (int r = 0; r < 4; ++r) {
            const float pr = __shfl_xor(ar[r], txr);
            const float pi = __shfl_xor(ai[r], txr);
            ar[r] = c0 * ar[r] + s0 * pi;
            ai[r] = c0 * ai[r] - s0 * pr;
          }
        }
      }
    }
  }
#pragma unroll
  for (int r = 0; r < 4; ++r) {
    Ure[(r * 64 + lane) * DIM + col] = ar[r];
    Uim[(r * 64 + lane) * DIM + col] = ai[r];
  }
}

// ---------------------------------------------------------------------------
// Kernel 2: A[n][k] = Re(U^H D U)[n][k], fp8 e4m3 (|A|<=1, RNE HW cvt), in
// PAIRED fragment order so one ds_read_b128 yields the A-fragments of TWO
// k-blocks (t=2tp, 2tp+1)  [verified rounds 9-10: absmax 0.0117 passes]:
//   nt=n>>4, c=n&15, t=k>>5, tp=t>>1, pr=t&1, q=(k>>3)&3, j=k&7
//   off = (((nt*4 + tp)*4 + q)*16 + c)*16 + pr*8 + j         (64 KB total)
// ---------------------------------------------------------------------------
__global__ __launch_bounds__(1024) void build_A(const float* __restrict__ Ure,
                                                const float* __restrict__ Uim,
                                                unsigned char* __restrict__ Af8) {
  __shared__ float partial[4][DIM];
  const int n = blockIdx.x;
  const int kk = threadIdx.x & 255;
  const int mc = threadIdx.x >> 8;  // 0..3
  float acc = 0.0f;
  for (int m = mc * 64; m < mc * 64 + 64; ++m) {
    const float sgn = (m < 128) ? 1.0f : -1.0f;
    const float ukr = sgn * Ure[m * DIM + n];
    const float uki = sgn * Uim[m * DIM + n];
    acc = fmaf(ukr, Ure[m * DIM + kk], acc);
    acc = fmaf(uki, Uim[m * DIM + kk], acc);
  }
  partial[mc][kk] = acc;
  __syncthreads();
  if (mc == 0) {
    const float v = partial[0][kk] + partial[1][kk] + partial[2][kk] + partial[3][kk];
    const int nt = n >> 4, c = n & 15;
    const int t = kk >> 5, tp = t >> 1, pr = t & 1;
    const int q = (kk >> 3) & 3, j = kk & 7;
    const int off = (((nt * 4 + tp) * 4 + q) * 16 + c) * 16 + pr * 8 + j;
    const int pk = __builtin_amdgcn_cvt_pk_fp8_f32(v, v, 0, false);
    Af8[off] = (unsigned char)(pk & 0xff);
  }
}

// ---------------------------------------------------------------------------
// Kernel 3 (fp8 MFMA, A fully LDS-resident, v3 = round-10 + 2-way batch
// tiling): each wave handles 32 batch elements in two psi groups; every
// ds_read_b128 feeds FOUR MFMAs (2 k-blocks x 2 groups) -> chip LDS reads
// halve to 268 MB (~3.4 us), leaving the kernel MFMA-bound (~8.5 us).
// Execution shape unchanged from the verified round-10 regime: 512-thread
// blocks, grid 512, 64 KB LDS, 2 blocks/CU, 16 waves/CU, 128-VGPR cap.
// Register budget: psi[2][8] i64 = 32 + ccg/ssg 16 + hd 8 + acc 8 + misc ~14
// = ~80 live; load hoisting bounded to 4 b128 (16 VGPR) by a REAL backedge
// every nt-tile (#pragma unroll 1, 16 iters) -> ~110 < 128, spill-free.
// Per-batch math bit-identical to round 10 -> absmax must stay 0.01171875.
// ---------------------------------------------------------------------------
__global__ __launch_bounds__(512) void qcnn_mfma(const float* __restrict__ x,
                                                 const unsigned char* __restrict__ Af8,
                                                 float* __restrict__ out) {
  __shared__ unsigned char sA[65536];  // full A, fp8, fragment-paired order
  const int tid = threadIdx.x;
  const int lane = tid & 63;
  const int w = __builtin_amdgcn_readfirstlane(tid >> 6);  // 0..7
  const int c = lane & 15;
  const int q = lane >> 4;
  const int lo = q & 1;
  const int hi = (q >> 1) & 1;
  const int bbase = blockIdx.x * 256 + w * 32;  // 32 batch per wave

  // stage full A once: 8 x 8 KB, block-cooperative, 16 B per thread per step
#pragma unroll
  for (int i = 0; i < 8; ++i) {
    __builtin_amdgcn_global_load_lds(
        (const __attribute__((address_space(1))) uint32_t*)(Af8 + i * 8192 +
                                                            w * 1024 + lane * 16),
        (__attribute__((address_space(3))) uint32_t*)(sA + i * 8192 + w * 1024),
        16, 0, 0);
  }
  __syncthreads();  // the only barrier in this kernel

  long psi[2][8];
  float ccg[2][4], ssg[2][4], hd[2][4];
#pragma unroll
  for (int G = 0; G < 2; ++G) {
    const int b = bbase + G * 16 + c;
    const float4* xv = (const float4*)(x + (size_t)b * 8);
    const float4 x0 = xv[0];
    const float4 x1 = xv[1];
    const float xs[8] = {x0.x, x0.y, x0.z, x0.w, x1.x, x1.y, x1.z, x1.w};
    float cc[8], ss[8];
#pragma unroll
    for (int u = 0; u < 8; ++u) {
      cc[u] = __cosf(0.5f * xs[u]);
      ss[u] = __sinf(0.5f * xs[u]);
    }
    // hs[j] = h[8*lo + j]
    float hs[8];
    {
      const float a = lo ? ss[4] : cc[4];
      const float b0 = a * cc[5], b1 = a * ss[5];
      const float c0 = b0 * cc[6], c1 = b0 * ss[6];
      const float c2 = b1 * cc[6], c3 = b1 * ss[6];
      hs[0] = c0 * cc[7]; hs[1] = c0 * ss[7];
      hs[2] = c1 * cc[7]; hs[3] = c1 * ss[7];
      hs[4] = c2 * cc[7]; hs[5] = c2 * ss[7];
      hs[6] = c3 * cc[7]; hs[7] = c3 * ss[7];
    }
    // gk[t] = g[2t + hi]
    float gk[8];
    {
      const float g3 = hi ? ss[3] : cc[3];
      const float d0 = cc[2] * g3, d1 = ss[2] * g3;
      const float e0 = cc[1] * d0, e1 = cc[1] * d1;
      const float e2 = ss[1] * d0, e3 = ss[1] * d1;
      gk[0] = cc[0] * e0; gk[1] = cc[0] * e1;
      gk[2] = cc[0] * e2; gk[3] = cc[0] * e3;
      gk[4] = ss[0] * e0; gk[5] = ss[0] * e1;
      gk[6] = ss[0] * e2; gk[7] = ss[0] * e3;
    }
    // hd[r] = h[8*hi + 4*lo + r]
    {
      const float head = (hi ? ss[4] : cc[4]) * (lo ? ss[5] : cc[5]);
      const float h0 = head * cc[6], h1 = head * ss[6];
      hd[G][0] = h0 * cc[7]; hd[G][1] = h0 * ss[7];
      hd[G][2] = h1 * cc[7]; hd[G][3] = h1 * ss[7];
    }
    // psi frag for k-block t, element j: psi_b[32t + 8q + j] = gk[t]*hs[j],
    // packed e4m3 bytes of an i64 (cvt_pk: lo byte = src0).
#pragma unroll
    for (int t = 0; t < 8; ++t) {
      int plo = __builtin_amdgcn_cvt_pk_fp8_f32(gk[t] * hs[0], gk[t] * hs[1], 0, false);
      plo = __builtin_amdgcn_cvt_pk_fp8_f32(gk[t] * hs[2], gk[t] * hs[3], plo, true);
      int phi = __builtin_amdgcn_cvt_pk_fp8_f32(gk[t] * hs[4], gk[t] * hs[5], 0, false);
      phi = __builtin_amdgcn_cvt_pk_fp8_f32(gk[t] * hs[6], gk[t] * hs[7], phi, true);
      psi[G][t] = (long)(((unsigned long)(unsigned)phi << 32) | (unsigned)plo);
    }
#pragma unroll
    for (int u = 0; u < 4; ++u) { ccg[G][u] = cc[u]; ssg[G][u] = ss[u]; }
  }

  float z0 = 0.0f, z1 = 0.0f;
#pragma unroll 1
  for (int nt = 0; nt < 16; ++nt) {  // REAL backedge: bounds load hoisting
    f32x4 acc0 = {0.0f, 0.0f, 0.0f, 0.0f};
    f32x4 acc1 = {0.0f, 0.0f, 0.0f, 0.0f};
#pragma unroll
    for (int tp = 0; tp < 4; ++tp) {
      const lng2 av = *(const lng2*)(sA + nt * 4096 + tp * 1024 + lane * 16);
      acc0 = __builtin_amdgcn_mfma_f32_16x16x32_fp8_fp8(av.x, psi[0][2 * tp], acc0, 0, 0, 0);
      acc0 = __builtin_amdgcn_mfma_f32_16x16x32_fp8_fp8(av.y, psi[0][2 * tp + 1], acc0, 0, 0, 0);
      acc1 = __builtin_amdgcn_mfma_f32_16x16x32_fp8_fp8(av.x, psi[1][2 * tp], acc1, 0, 0, 0);
      acc1 = __builtin_amdgcn_mfma_f32_16x16x32_fp8_fp8(av.y, psi[1][2 * tp + 1], acc1, 0, 0, 0);
    }
    // rows n = nt*16 + q*4 + r -> psi[b][n] = g[nt] * hd[r]; nt is uniform,
    // bit-selects compile to scalar tests + cndmask.
    const float gv0 = ((nt & 8) ? ssg[0][0] : ccg[0][0]) *
                      ((nt & 4) ? ssg[0][1] : ccg[0][1]) *
                      ((nt & 2) ? ssg[0][2] : ccg[0][2]) *
                      ((nt & 1) ? ssg[0][3] : ccg[0][3]);
    const float gv1 = ((nt & 8) ? ssg[1][0] : ccg[1][0]) *
                      ((nt & 4) ? ssg[1][1] : ccg[1][1]) *
                      ((nt & 2) ? ssg[1][2] : ccg[1][2]) *
                      ((nt & 1) ? ssg[1][3] : ccg[1][3]);
    const float dot0 = hd[0][0] * acc0[0] + hd[0][1] * acc0[1] +
                       hd[0][2] * acc0[2] + hd[0][3] * acc0[3];
    const float dot1 = hd[1][0] * acc1[0] + hd[1][1] * acc1[1] +
                       hd[1][2] * acc1[2] + hd[1][3] * acc1[3];
    z0 = fmaf(gv0, dot0, z0);
    z1 = fmaf(gv1, dot1, z1);
  }

  // reduce across the 4 q-groups (same col lives in lanes c+16m)
  z0 += __shfl_xor(z0, 16);
  z0 += __shfl_xor(z0, 32);
  z1 += __shfl_xor(z1, 16);
  z1 += __shfl_xor(z1, 32);
  if (lane < 16) {
    out[bbase + lane] = 1.0f / (1.0f + __expf(-z0));
    out[bbase + 16 + lane] = 1.0f / (1.0f + __expf(-z1));
  }
}

// ---------------------------------------------------------------------------
// ws layout: Ure[65536] f32 | Uim[65536] f32 | Af8[65536] e4m3  = 576 KB.
// ---------------------------------------------------------------------------
extern "C" void kernel_launch(void* const* d_in, const int* in_sizes, int n_in,
                              void* d_out, int out_size, void* d_ws, size_t ws_size,
                              hipStream_t stream) {
  const float* x = (const float*)d_in[0];
  const float* params = (const float*)d_in[1];
  float* out = (float*)d_out;
  float* Ure = (float*)d_ws;
  float* Uim = Ure + DIM * DIM;
  unsigned char* Af8 = (unsigned char*)(Uim + DIM * DIM);

  build_U<<<DIM, 64, 0, stream>>>(params, Ure, Uim);
  build_A<<<DIM, 1024, 0, stream>>>(Ure, Uim, Af8);

  const int B = in_sizes[0] / NQ;  // 131072
  qcnn_mfma<<<B / 256, 512, 0, stream>>>(x, Af8, out);
}